// Round 10
// baseline (177.512 us; speedup 1.0000x reference)
//
#include <hip/hip_runtime.h>
#include <hip/hip_bf16.h>

typedef short short8 __attribute__((ext_vector_type(8)));
typedef float float4_ __attribute__((ext_vector_type(4)));
typedef unsigned short ushort_t;
typedef unsigned int uint32_t_;
typedef uint32_t_ uint2v __attribute__((ext_vector_type(2)));
typedef uint32_t_ uint4v __attribute__((ext_vector_type(4)));

#define SCL 0.1803368801111f   // log2(e)/sqrt(64), folded into Q via gemm1 epilogue

__device__ __forceinline__ ushort_t f2bf(float f) {
    uint32_t_ u = __builtin_bit_cast(uint32_t_, f);
    u = (u + 0x7fffu + ((u >> 16) & 1u)) >> 16;
    return (ushort_t)u;
}

// pack two floats to bf16x2 (round-half-up on mantissa), a in low half
__device__ __forceinline__ uint32_t_ pack_bf16(float a, float b) {
    uint32_t_ ua = __builtin_bit_cast(uint32_t_, a) + 0x8000u;
    uint32_t_ ub = __builtin_bit_cast(uint32_t_, b) + 0x8000u;
    return __builtin_amdgcn_perm(ub, ua, 0x07060302);
}

// 1-instr pack (RTNE == f2bf rounding), lo in low half
__device__ __forceinline__ uint32_t_ cvt_pk_bf16(float lo, float hi) {
    uint32_t_ r;
    asm("v_cvt_pk_bf16_f32 %0, %1, %2" : "=v"(r) : "v"(lo), "v"(hi));
    return r;
}

#define MFMA32(a, b, c) __builtin_amdgcn_mfma_f32_16x16x32_bf16(a, b, c, 0, 0, 0)

#define GLD_LDS16(g, l) __builtin_amdgcn_global_load_lds( \
    (const __attribute__((address_space(1))) void*)(g),   \
    (__attribute__((address_space(3))) void*)(l), 16, 0, 0)

// ---------------- prep: transpose Wqkv + transpose Wout (x-cvt now inside gemm1) -----
// blocks 0..3071: Wqkv [1024][3072] -> [3072][1024]; 3072..4095: Wout -> WoutT.
// (r8-verified form; x is consumed fp32 by gemm1's DMA staging — no x_bf pass.)
__global__ __launch_bounds__(256)
void prep_k(const float* __restrict__ Wqkv, ushort_t* __restrict__ WqkvT,
            const float* __restrict__ Wout, ushort_t* __restrict__ WoutT) {
    __shared__ float tile[32][33];
    const int id = blockIdx.x;
    const int tid = threadIdx.x;
    const float* in;
    ushort_t* out;
    int N, K, n0, k0;
    if (id < 3072) {
        in = Wqkv; out = WqkvT; N = 3072; K = 1024;
        n0 = (id % 96) * 32; k0 = (id / 96) * 32;
    } else {
        int t = id - 3072;
        in = Wout; out = WoutT; N = 1024; K = 1024;
        n0 = (t & 31) * 32; k0 = (t >> 5) * 32;
    }
    int tx = tid & 31, ty = tid >> 5;
    #pragma unroll
    for (int i = 0; i < 32; i += 8)
        tile[ty + i][tx] = in[(size_t)(k0 + ty + i) * N + n0 + tx];
    __syncthreads();
    #pragma unroll
    for (int i = 0; i < 32; i += 8)
        out[(size_t)(n0 + ty + i) * K + k0 + tx] = f2bf(tile[tx][ty + i]);
}

// ---------------- double-buffered GEMM: C = A[M][K] @ Bt[N][K]^T + bias ----------------
// BM=128, BK=32, single barrier per k-step, global_load_lds staging, XOR-swizzled LDS,
// XCD-aware block swizzle.
// AFP32: A is fp32 (x) staged via global_load_lds into a 16 KB A-region ([128 rows]
// [128 B], 8 slots of 16B, slot XOR z=(row>>1)&7 — flash-verified swizzle family),
// converted bf16 (RNE, == f2bf bits) during the LDS->reg fragment read:
// 2x ds_read_b128 + 4x v_cvt_pk per frag. DMA staging path preserved (r8 lesson:
// reg-staging = -26%, m151). SETB 24 KB -> 48 KB total, still 3 blocks/CU.
// QKV_EPI: N=3072 fused epilogue — Q cols scaled->qk, K cols->qk, V cols -> Vt_out.
template <int TN, bool QKV_EPI, bool AFP32>
__global__ __launch_bounds__(256, TN == 128 ? 3 : 4)
void gemm_dbuf_k(const void* __restrict__ Aptr, const ushort_t* __restrict__ Bt,
                 const float* __restrict__ bias, void* __restrict__ C,
                 ushort_t* __restrict__ Vt_out, int M, int N, int K) {
    constexpr int NB     = TN / 32;            // N acc frags per wave
    constexpr int ABYTES = AFP32 ? 16384 : 8192;
    constexpr int SETB   = ABYTES + TN * 64;   // bytes per buffer set
    __shared__ char smem[2 * SETB];
    const int tid  = threadIdx.x;
    // XCD swizzle (bijective: nwg multiple of 8)
    const int nwg = gridDim.x * gridDim.y;
    const int id  = blockIdx.y * gridDim.x + blockIdx.x;
    const int sid = (id & 7) * (nwg >> 3) + (id >> 3);
    const int m0  = (sid / gridDim.x) * 128;
    const int n0  = (sid % gridDim.x) * TN;
    const int w    = tid >> 6;
    const int lane = tid & 63;
    const int wm   = (w >> 1) * 64;
    const int wn   = (w & 1) * (TN / 2);
    const int quad = lane >> 4;
    const int l16  = lane & 15;

    // B staging: 64B rows, 4 lanes/row, 16B chunk slot = seg ^ ((row>>1)&3)
    const int sr = 16 * w + (lane >> 2);
    const int sc = ((lane & 3) ^ ((sr >> 1) & 3)) * 8;
    const ushort_t* bg0 = Bt + (size_t)(n0 + sr) * K + sc;
    const ushort_t* bg1 = Bt + (size_t)(n0 + sr + 64) * K + sc;   // TN==128 only

    // A staging
    const ushort_t* ag0 = nullptr;
    const ushort_t* ag1 = nullptr;
    const float* af32[4];
    if constexpr (AFP32) {
        // fp32: 128B rows, 8 lanes/row, slot = s7 ^ ((row>>1)&7); 4 calls/wave (8 rows ea)
        #pragma unroll
        for (int j = 0; j < 4; j++) {
            int row = 32 * w + 8 * j + (lane >> 3);
            int cs  = ((lane & 7) ^ ((row >> 1) & 7)) * 4;   // col in fp32 elems
            af32[j] = (const float*)Aptr + (size_t)(m0 + row) * K + cs;
        }
    } else {
        ag0 = (const ushort_t*)Aptr + (size_t)(m0 + sr) * K + sc;
        ag1 = ag0 + (size_t)64 * K;
    }

    // fragment read offsets
    const int sw8 = (l16 >> 1) & 7;
    int aoff[4], aoffA[4][2], boff[NB];
    #pragma unroll
    for (int i = 0; i < 4; i++) {
        int row = wm + i * 16 + l16;
        if (AFP32) {
            aoffA[i][0] = row * 128 + (((2 * quad)     ^ sw8) * 16);
            aoffA[i][1] = row * 128 + (((2 * quad + 1) ^ sw8) * 16);
        } else {
            aoff[i] = row * 64 + ((quad ^ ((row >> 1) & 3)) * 16);
        }
    }
    #pragma unroll
    for (int i = 0; i < NB; i++) {
        int row = wn + i * 16 + l16;
        boff[i] = ABYTES + row * 64 + ((quad ^ ((row >> 1) & 3)) * 16);
    }

    float4_ acc[4][NB] = {};
    const int NIT = K >> 5;

    // prologue: stage tile 0 (all via DMA)
    {
        char* dA = smem;
        char* dB = smem + ABYTES;
        if constexpr (AFP32) {
            #pragma unroll
            for (int j = 0; j < 4; j++)
                GLD_LDS16(af32[j], dA + 4096 * w + 1024 * j);
        } else {
            GLD_LDS16(ag0, dA + 1024 * w);
            GLD_LDS16(ag1, dA + 4096 + 1024 * w);
        }
        GLD_LDS16(bg0, dB + 1024 * w);
        if (TN == 128) GLD_LDS16(bg1, dB + 4096 + 1024 * w);
    }

    for (int it = 0; it < NIT; ++it) {
        __syncthreads();                       // drains DMA(it); all prior frag reads done
        if (it + 1 < NIT) {
            const int nk = (it + 1) * 32;
            char* dA = smem + ((it + 1) & 1) * SETB;
            char* dB = dA + ABYTES;
            if constexpr (AFP32) {
                #pragma unroll
                for (int j = 0; j < 4; j++)
                    GLD_LDS16(af32[j] + nk, dA + 4096 * w + 1024 * j);
            } else {
                GLD_LDS16(ag0 + nk, dA + 1024 * w);
                GLD_LDS16(ag1 + nk, dA + 4096 + 1024 * w);
            }
            GLD_LDS16(bg0 + nk, dB + 1024 * w);
            if (TN == 128) GLD_LDS16(bg1 + nk, dB + 4096 + 1024 * w);
        }
        const char* base = smem + (it & 1) * SETB;
        short8 af[4], bf[NB];
        #pragma unroll
        for (int i = 0; i < 4; i++) {
            if constexpr (AFP32) {
                float4_ x0 = *(const float4_*)(base + aoffA[i][0]);
                float4_ x1 = *(const float4_*)(base + aoffA[i][1]);
                uint4v u;
                u.x = cvt_pk_bf16(x0[0], x0[1]);
                u.y = cvt_pk_bf16(x0[2], x0[3]);
                u.z = cvt_pk_bf16(x1[0], x1[1]);
                u.w = cvt_pk_bf16(x1[2], x1[3]);
                af[i] = __builtin_bit_cast(short8, u);
            } else {
                af[i] = *(const short8*)(base + aoff[i]);
            }
        }
        #pragma unroll
        for (int i = 0; i < NB; i++) bf[i] = *(const short8*)(base + boff[i]);
        #pragma unroll
        for (int mi = 0; mi < 4; mi++)
            #pragma unroll
            for (int ni = 0; ni < NB; ni++)
                acc[mi][ni] = MFMA32(af[mi], bf[ni], acc[mi][ni]);
    }

    #pragma unroll
    for (int mi = 0; mi < 4; mi++) {
        int row = m0 + wm + mi * 16 + quad * 4;
        #pragma unroll
        for (int ni = 0; ni < NB; ni++) {
            int col = n0 + wn + ni * 16 + l16;
            float bb = bias[col];
            if (QKV_EPI) {
                if (col < 2048) {
                    float sc2 = (col < 1024) ? SCL : 1.0f;
                    #pragma unroll
                    for (int r = 0; r < 4; r++)
                        ((ushort_t*)C)[(size_t)(row + r) * 2048 + col] =
                            f2bf((acc[mi][ni][r] + bb) * sc2);
                } else {
                    // V^T permuted: s' = (s&~31) | quad*8 | (mi&1)*4 | r
                    int s0v  = row & 2047;
                    int spos = (s0v & ~31) | (quad << 3) | ((mi & 1) << 2);
                    size_t vrow = (size_t)((row >> 11) * 1024 + (col - 2048));
                    float v0 = acc[mi][ni][0] + bb, v1 = acc[mi][ni][1] + bb;
                    float v2 = acc[mi][ni][2] + bb, v3 = acc[mi][ni][3] + bb;
                    uint2v pk;
                    pk.x = pack_bf16(v0, v1);
                    pk.y = pack_bf16(v2, v3);
                    *(uint2v*)(Vt_out + vrow * 2048 + spos) = pk;
                }
            } else {
                #pragma unroll
                for (int r = 0; r < 4; r++)
                    ((float*)C)[(size_t)(row + r) * N + col] = acc[mi][ni][r] + bb;
            }
        }
    }
}

// ---------------- flash attention v10 (frozen, passing): 8 waves / q-tile 128 --------
// qk bf16 [tok][2048] = [q(1024,pre-scaled) | k(1024)]; vt bf16 [bh*64+d][2048] s-permuted.
// grid (32 bh, 16 q-tiles) x 512 thr. Waves: qh=w>>1 (0..3, 32 q-rows each), kh=w&1.
// PV pipelined one tile behind QK; fp32 scalar lsum (bf16 ones-MFMA denominator fails
// numerics, r3); per-wave staging 1 K-row-block + 1 V-row-block per iter.
__global__ __launch_bounds__(512, 4)
void flash_attn_k(const ushort_t* __restrict__ qk, const ushort_t* __restrict__ vt,
                  ushort_t* __restrict__ out) {
    __shared__ char smem[49152];
    const int bh = blockIdx.x;
    const int b  = bh >> 4, h = bh & 15;
    const int q0 = blockIdx.y * 128;
    const int tid  = threadIdx.x;
    const int w    = tid >> 6;        // 0..7
    const int lane = tid & 63;
    const int quad = lane >> 4;
    const int l16  = lane & 15;
    const int qh   = w >> 1;          // 0..3
    const int kh   = w & 1;
    const size_t tok0 = (size_t)b * 2048;
    const int hq = h * 64;

    const int s7  = lane & 7;
    const int rk  = 8 * w + (lane >> 3);               // kv/d row 0..63
    const int ck  = (s7 ^ ((rk >> 1) & 7)) * 8;
    const int rq0 = 16 * w + (lane >> 3), rq1 = rq0 + 8;   // q rows 0..127
    const int cq0 = (s7 ^ ((rq0 >> 1) & 7)) * 8;
    const int cq1 = (s7 ^ ((rq1 >> 1) & 7)) * 8;
    const ushort_t* qg0 = qk + (tok0 + q0 + rq0) * 2048 + hq + cq0;
    const ushort_t* qg1 = qk + (tok0 + q0 + rq1) * 2048 + hq + cq1;
    const ushort_t* kg  = qk + (tok0 + rk) * 2048 + 1024 + hq + ck;
    const ushort_t* vg  = vt + (size_t)(bh * 64 + rk) * 2048 + ck;
    char* stK = smem + 1024 * w;
    char* stV = smem + 8192 + 1024 * w;
    char* stQ = smem + 32768 + 2048 * w;

    // prologue: Q -> Q area; K0/V0 -> B0
    GLD_LDS16(qg0, stQ);
    GLD_LDS16(qg1, stQ + 1024);
    GLD_LDS16(kg, stK);
    GLD_LDS16(vg, stV);
    __syncthreads();

    const int sw = (l16 >> 1) & 7;   // row-swizzle term for all frag reads
    short8 qf[2][2];
    #pragma unroll
    for (int sub = 0; sub < 2; sub++)
        #pragma unroll
        for (int kk = 0; kk < 2; kk++) {
            int row = qh * 32 + sub * 16 + l16;
            qf[sub][kk] = *(const short8*)(smem + 32768 + row * 128 +
                                           (((kk * 4 + quad) ^ sw) * 16));
        }

    int koff[2][2], voff[4];
    #pragma unroll
    for (int mi = 0; mi < 2; mi++)
        #pragma unroll
        for (int kk = 0; kk < 2; kk++) {
            int row = kh * 32 + mi * 16 + l16;
            koff[mi][kk] = row * 128 + (((kk * 4 + quad) ^ sw) * 16);
        }
    #pragma unroll
    for (int di = 0; di < 4; di++) {
        int row = di * 16 + l16;
        voff[di] = 8192 + row * 128 + (((kh * 4 + quad) ^ sw) * 16);
    }

    float4_ ot[2][4] = {};        // O^T: d = di*16+quad*4+r, q = qh*32+sub*16+l16
    float lsum[2] = {0.f, 0.f};
    short8 vprev[4];              // V frags of tile t-1 (time-shared reg block)
    short8 bpprev[2];             // packed P of tile t-1

    const ushort_t* kp = kg + (size_t)64 * 2048;
    const ushort_t* vp = vg + 64;

    // ---- peeled iter 0: QK(0), stash V(0)/P(0) in regs, no PV yet ----
    {
        __syncthreads();          // qf reads drained; DMA(0) done
        GLD_LDS16(kp, stK + 16384);
        GLD_LDS16(vp, stV + 16384);
        kp += (size_t)64 * 2048;
        vp += 64;
        const char* base = smem;
        float4_ st[2][2];
        #pragma unroll
        for (int mi = 0; mi < 2; mi++) {
            short8 kf0 = *(const short8*)(base + koff[mi][0]);
            short8 kf1 = *(const short8*)(base + koff[mi][1]);
            #pragma unroll
            for (int sub = 0; sub < 2; sub++) {
                float4_ z = {0.f, 0.f, 0.f, 0.f};
                z = MFMA32(kf0, qf[sub][0], z);
                z = MFMA32(kf1, qf[sub][1], z);
                st[mi][sub] = z;
            }
        }
        #pragma unroll
        for (int di = 0; di < 4; di++)
            vprev[di] = *(const short8*)(base + voff[di]);
        #pragma unroll
        for (int sub = 0; sub < 2; sub++) {
            uint4v u;
            #pragma unroll
            for (int mi = 0; mi < 2; mi++) {
                float p0 = __builtin_amdgcn_exp2f(st[mi][sub][0]);
                float p1 = __builtin_amdgcn_exp2f(st[mi][sub][1]);
                float p2 = __builtin_amdgcn_exp2f(st[mi][sub][2]);
                float p3 = __builtin_amdgcn_exp2f(st[mi][sub][3]);
                lsum[sub] += (p0 + p1) + (p2 + p3);
                if (mi == 0) { u.x = cvt_pk_bf16(p0, p1); u.y = cvt_pk_bf16(p2, p3); }
                else         { u.z = cvt_pk_bf16(p0, p1); u.w = cvt_pk_bf16(p2, p3); }
            }
            bpprev[sub] = __builtin_bit_cast(short8, u);
        }
    }

    // ---- main loop: tiles 1..31; PV runs one tile behind ----
    for (int kt = 64; kt < 2048; kt += 64) {
        __syncthreads();          // drains DMA(kt); tile(kt-64) LDS reads all done
        const int set = (kt >> 6) & 1;
        if (kt + 64 < 2048) {
            const int nb = (set ^ 1) * 16384;
            GLD_LDS16(kp, stK + nb);
            GLD_LDS16(vp, stV + nb);
            kp += (size_t)64 * 2048;
            vp += 64;
        }
        const char* base = smem + set * 16384;

        // QK(t): kv = kt + kh*32 + mi*16 + quad*4 + r, q = qh*32 + sub*16 + l16
        float4_ st[2][2];
        #pragma unroll
        for (int mi = 0; mi < 2; mi++) {
            short8 kf0 = *(const short8*)(base + koff[mi][0]);
            short8 kf1 = *(const short8*)(base + koff[mi][1]);
            #pragma unroll
            for (int sub = 0; sub < 2; sub++) {
                float4_ z = {0.f, 0.f, 0.f, 0.f};
                z = MFMA32(kf0, qf[sub][0], z);
                z = MFMA32(kf1, qf[sub][1], z);
                st[mi][sub] = z;
            }
        }

        // PV(t-1) from registers — independent of QK(t), hides its latency
        #pragma unroll
        for (int di = 0; di < 4; di++)
            #pragma unroll
            for (int sub = 0; sub < 2; sub++)
                ot[sub][di] = MFMA32(vprev[di], bpprev[sub], ot[sub][di]);

        // reload V(t) into the freed reg block (needed next iter)
        #pragma unroll
        for (int di = 0; di < 4; di++)
            vprev[di] = *(const short8*)(base + voff[di]);

        // exp/pack(t) -> bpprev, fp32 lsum (QK latency covered by PV MFMAs)
        #pragma unroll
        for (int sub = 0; sub < 2; sub++) {
            uint4v u;
            #pragma unroll
            for (int mi = 0; mi < 2; mi++) {
                float p0 = __builtin_amdgcn_exp2f(st[mi][sub][0]);
                float p1 = __builtin_amdgcn_exp2f(st[mi][sub][1]);
                float p2 = __builtin_amdgcn_exp2f(st[mi][sub][2]);
                float p3 = __builtin_amdgcn_exp2f(st[mi][sub][3]);
                lsum[sub] += (p0 + p1) + (p2 + p3);
                if (mi == 0) { u.x = cvt_pk_bf16(p0, p1); u.y = cvt_pk_bf16(p2, p3); }
                else         { u.z = cvt_pk_bf16(p0, p1); u.w = cvt_pk_bf16(p2, p3); }
            }
            bpprev[sub] = __builtin_bit_cast(short8, u);
        }
    }

    // ---- drain: PV(31) ----
    #pragma unroll
    for (int di = 0; di < 4; di++)
        #pragma unroll
        for (int sub = 0; sub < 2; sub++)
            ot[sub][di] = MFMA32(vprev[di], bpprev[sub], ot[sub][di]);

    // reduce l over quads
    #pragma unroll
    for (int sub = 0; sub < 2; sub++) {
        float t = lsum[sub];
        t += __shfl_xor(t, 16, 64);
        t += __shfl_xor(t, 32, 64);
        lsum[sub] = t;
    }

    // combine kv-halves across wave pairs through LDS (overlay on buffers)
    float* Obuf = (float*)smem;                 // [128][68]
    float* lbuf = (float*)(smem + 34816);       // [128][2]
    __syncthreads();                            // all buffer reads done
    #pragma unroll
    for (int sub = 0; sub < 2; sub++)
        lbuf[(qh * 32 + sub * 16 + l16) * 2 + kh] = lsum[sub];
    if (kh == 1) {
        #pragma unroll
        for (int sub = 0; sub < 2; sub++)
            #pragma unroll
            for (int di = 0; di < 4; di++)
                *(float4_*)&Obuf[(qh * 32 + sub * 16 + l16) * 68 + di * 16 + quad * 4] = ot[sub][di];
    }
    __syncthreads();
    if (kh == 0) {
        #pragma unroll
        for (int sub = 0; sub < 2; sub++)
            #pragma unroll
            for (int di = 0; di < 4; di++) {
                float4_* p = (float4_*)&Obuf[(qh * 32 + sub * 16 + l16) * 68 + di * 16 + quad * 4];
                *p = *p + ot[sub][di];
            }
    }
    __syncthreads();

    // normalize + coalesced store (512 thr -> 128 rows x 4 chunks)
    {
        int q  = tid >> 2;
        int ds = (tid & 3) * 16;
        float linv = 1.0f / (lbuf[q * 2] + lbuf[q * 2 + 1]);
        const float* ob = &Obuf[q * 68 + ds];
        float4_ v0 = *(const float4_*)(ob);
        float4_ v1 = *(const float4_*)(ob + 4);
        float4_ v2 = *(const float4_*)(ob + 8);
        float4_ v3 = *(const float4_*)(ob + 12);
        uint4v d0, d1;
        d0.x = pack_bf16(v0[0] * linv, v0[1] * linv);
        d0.y = pack_bf16(v0[2] * linv, v0[3] * linv);
        d0.z = pack_bf16(v1[0] * linv, v1[1] * linv);
        d0.w = pack_bf16(v1[2] * linv, v1[3] * linv);
        d1.x = pack_bf16(v2[0] * linv, v2[1] * linv);
        d1.y = pack_bf16(v2[2] * linv, v2[3] * linv);
        d1.z = pack_bf16(v3[0] * linv, v3[1] * linv);
        d1.w = pack_bf16(v3[2] * linv, v3[3] * linv);
        ushort_t* dst = out + (tok0 + q0 + (size_t)q) * 1024 + hq + ds;
        *(uint4v*)(dst)     = d0;
        *(uint4v*)(dst + 8) = d1;
    }
}

extern "C" void kernel_launch(void* const* d_in, const int* in_sizes, int n_in,
                              void* d_out, int out_size, void* d_ws, size_t ws_size,
                              hipStream_t stream) {
    const float* x    = (const float*)d_in[0];  // [2,2048,1024]
    const float* Wqkv = (const float*)d_in[1];  // [1024,3072]
    const float* bqkv = (const float*)d_in[2];  // [3072]
    const float* Wout = (const float*)d_in[3];  // [1024,1024]
    const float* bout = (const float*)d_in[4];  // [1024]
    float* out = (float*)d_out;                 // [2,2048,1024] fp32

    char* ws = (char*)d_ws;
    ushort_t* WqkvT   = (ushort_t*)(ws + 8388608);   // 6 MB
    ushort_t* WoutT   = (ushort_t*)(ws + 14680064);  // 2 MB
    ushort_t* qk_bf   = (ushort_t*)(ws + 16777216);  // [4096][2048] = 16 MB
    ushort_t* vt_bf   = (ushort_t*)(ws + 33554432);  // [2048][2048] = 8 MB
    ushort_t* attn_bf = (ushort_t*)(ws + 41943040);  // 8 MB

    prep_k<<<4096, 256, 0, stream>>>(Wqkv, WqkvT, Wout, WoutT);

    gemm_dbuf_k<128, true, true><<<dim3(24, 32), 256, 0, stream>>>(
        (const void*)x, WqkvT, bqkv, (void*)qk_bf, vt_bf, 4096, 3072, 1024);

    flash_attn_k<<<dim3(32, 16), 512, 0, stream>>>(qk_bf, vt_bf, attn_bf);

    gemm_dbuf_k<64, false, false><<<dim3(16, 32), 256, 0, stream>>>(
        (const void*)attn_bf, WoutT, bout, (void*)out, nullptr, 4096, 1024, 1024);
}

// Round 11
// 171.721 us; speedup vs baseline: 1.0337x; 1.0337x over previous
//
#include <hip/hip_runtime.h>
#include <hip/hip_bf16.h>

typedef short short8 __attribute__((ext_vector_type(8)));
typedef float float4_ __attribute__((ext_vector_type(4)));
typedef unsigned short ushort_t;
typedef unsigned int uint32_t_;
typedef uint32_t_ uint2v __attribute__((ext_vector_type(2)));
typedef uint32_t_ uint4v __attribute__((ext_vector_type(4)));

#define SCL 0.1803368801111f   // log2(e)/sqrt(64), folded into Q via gemm1 epilogue

__device__ __forceinline__ ushort_t f2bf(float f) {
    uint32_t_ u = __builtin_bit_cast(uint32_t_, f);
    u = (u + 0x7fffu + ((u >> 16) & 1u)) >> 16;
    return (ushort_t)u;
}

// pack two floats to bf16x2 (round-half-up on mantissa), a in low half
__device__ __forceinline__ uint32_t_ pack_bf16(float a, float b) {
    uint32_t_ ua = __builtin_bit_cast(uint32_t_, a) + 0x8000u;
    uint32_t_ ub = __builtin_bit_cast(uint32_t_, b) + 0x8000u;
    return __builtin_amdgcn_perm(ub, ua, 0x07060302);
}

// 1-instr pack (RTNE), lo in low half
__device__ __forceinline__ uint32_t_ cvt_pk_bf16(float lo, float hi) {
    uint32_t_ r;
    asm("v_cvt_pk_bf16_f32 %0, %1, %2" : "=v"(r) : "v"(lo), "v"(hi));
    return r;
}

#define MFMA32(a, b, c) __builtin_amdgcn_mfma_f32_16x16x32_bf16(a, b, c, 0, 0, 0)

#define GLD_LDS16(g, l) __builtin_amdgcn_global_load_lds( \
    (const __attribute__((address_space(1))) void*)(g),   \
    (__attribute__((address_space(3))) void*)(l), 16, 0, 0)

// ---------------- merged prep: cvt x + transpose Wqkv + transpose Wout ----------------
// blocks 0..2047: cvt x (fp32->bf16, 8 elem/thread); 2048..5119: Wqkv -> WqkvT;
// 5120..6143: Wout -> WoutT.
// NOTE (r8/r10 lessons): the x_bf precompute is LOAD-BEARING. Fusing x-cvt into gemm1
// fails both ways: reg-staging = -26% (m151, r8: MfmaUtil 25->17.7), and fp32-A LDS
// staging = 8-way bank conflicts (r10: conflicts 0->3.1M, 128B rows alias all banks,
// row-stride % 128B-wrap == 0). GLD_LDS + bf16 64B rows in the GEMMs are sacred.
__global__ __launch_bounds__(256)
void prep_k(const float* __restrict__ x, ushort_t* __restrict__ x_bf,
            const float* __restrict__ Wqkv, ushort_t* __restrict__ WqkvT,
            const float* __restrict__ Wout, ushort_t* __restrict__ WoutT) {
    __shared__ float tile[32][33];
    const int id = blockIdx.x;
    const int tid = threadIdx.x;
    if (id < 2048) {
        int i = (id * 256 + tid) * 8;
        float4 v0 = *(const float4*)(x + i);
        float4 v1 = *(const float4*)(x + i + 4);
        uint4v d;
        d.x = (uint32_t_)f2bf(v0.x) | ((uint32_t_)f2bf(v0.y) << 16);
        d.y = (uint32_t_)f2bf(v0.z) | ((uint32_t_)f2bf(v0.w) << 16);
        d.z = (uint32_t_)f2bf(v1.x) | ((uint32_t_)f2bf(v1.y) << 16);
        d.w = (uint32_t_)f2bf(v1.z) | ((uint32_t_)f2bf(v1.w) << 16);
        *(uint4v*)(x_bf + i) = d;
        return;
    }
    const float* in;
    ushort_t* out;
    int N, K, n0, k0;
    if (id < 5120) {
        int t = id - 2048;
        in = Wqkv; out = WqkvT; N = 3072; K = 1024;
        n0 = (t % 96) * 32; k0 = (t / 96) * 32;
    } else {
        int t = id - 5120;
        in = Wout; out = WoutT; N = 1024; K = 1024;
        n0 = (t & 31) * 32; k0 = (t >> 5) * 32;
    }
    int tx = tid & 31, ty = tid >> 5;
    #pragma unroll
    for (int i = 0; i < 32; i += 8)
        tile[ty + i][tx] = in[(size_t)(k0 + ty + i) * N + n0 + tx];
    __syncthreads();
    #pragma unroll
    for (int i = 0; i < 32; i += 8)
        out[(size_t)(n0 + ty + i) * K + k0 + tx] = f2bf(tile[tx][ty + i]);
}

// ---------------- double-buffered GEMM: C = A[M][K] @ Bt[N][K]^T + bias ----------------
// BM=128, BK=32, single barrier per k-step, global_load_lds staging, XOR-swizzled LDS.
// XCD-aware blockIdx swizzle: contiguous tile chunk per XCD (nwg % 8 == 0 for both uses).
template <int TN, bool QKV_EPI>
__global__ __launch_bounds__(256, TN == 128 ? 3 : 4)
void gemm_dbuf_k(const ushort_t* __restrict__ A, const ushort_t* __restrict__ Bt,
                 const float* __restrict__ bias, void* __restrict__ C,
                 ushort_t* __restrict__ Vt_out, int M, int N, int K) {
    constexpr int NB   = TN / 32;           // N acc frags per wave
    constexpr int SETB = 8192 + TN * 64;    // bytes per buffer set
    __shared__ char smem[2 * SETB];
    const int tid  = threadIdx.x;
    // XCD swizzle (bijective: nwg multiple of 8)
    const int nwg = gridDim.x * gridDim.y;
    const int id  = blockIdx.y * gridDim.x + blockIdx.x;
    const int sid = (id & 7) * (nwg >> 3) + (id >> 3);
    const int m0  = (sid / gridDim.x) * 128;
    const int n0  = (sid % gridDim.x) * TN;
    const int w    = tid >> 6;
    const int lane = tid & 63;
    const int wm   = (w >> 1) * 64;
    const int wn   = (w & 1) * (TN / 2);
    const int quad = lane >> 4;
    const int l16  = lane & 15;

    // staging: 64B rows, 4 lanes/row, 16B chunk slot = seg ^ ((row>>1)&3)
    const int sr = 16 * w + (lane >> 2);
    const int sc = ((lane & 3) ^ ((sr >> 1) & 3)) * 8;
    const ushort_t* ag0 = A  + (size_t)(m0 + sr) * K + sc;
    const ushort_t* ag1 = A  + (size_t)(m0 + sr + 64) * K + sc;
    const ushort_t* bg0 = Bt + (size_t)(n0 + sr) * K + sc;
    const ushort_t* bg1 = Bt + (size_t)(n0 + sr + 64) * K + sc;   // TN==128 only
    char* sA = smem + 1024 * w;
    char* sB = smem + 8192 + 1024 * w;

    int aoff[4], boff[NB];
    #pragma unroll
    for (int i = 0; i < 4; i++) {
        int row = wm + i * 16 + l16;
        aoff[i] = row * 64 + ((quad ^ ((row >> 1) & 3)) * 16);
    }
    #pragma unroll
    for (int i = 0; i < NB; i++) {
        int row = wn + i * 16 + l16;
        boff[i] = 8192 + row * 64 + ((quad ^ ((row >> 1) & 3)) * 16);
    }

    float4_ acc[4][NB] = {};
    const int NIT = K >> 5;

    GLD_LDS16(ag0, sA);
    GLD_LDS16(ag1, sA + 4096);
    GLD_LDS16(bg0, sB);
    if (TN == 128) GLD_LDS16(bg1, sB + 4096);

    for (int it = 0; it < NIT; ++it) {
        __syncthreads();                       // drains DMA(it); all prior frag reads done
        if (it + 1 < NIT) {
            const int nk = (it + 1) * 32;
            char* dA = sA + ((it + 1) & 1) * SETB;
            char* dB = sB + ((it + 1) & 1) * SETB;
            GLD_LDS16(ag0 + nk, dA);
            GLD_LDS16(ag1 + nk, dA + 4096);
            GLD_LDS16(bg0 + nk, dB);
            if (TN == 128) GLD_LDS16(bg1 + nk, dB + 4096);
        }
        const char* base = smem + (it & 1) * SETB;
        short8 af[4], bf[NB];
        #pragma unroll
        for (int i = 0; i < 4; i++)  af[i] = *(const short8*)(base + aoff[i]);
        #pragma unroll
        for (int i = 0; i < NB; i++) bf[i] = *(const short8*)(base + boff[i]);
        #pragma unroll
        for (int mi = 0; mi < 4; mi++)
            #pragma unroll
            for (int ni = 0; ni < NB; ni++)
                acc[mi][ni] = MFMA32(af[mi], bf[ni], acc[mi][ni]);
    }

    #pragma unroll
    for (int mi = 0; mi < 4; mi++) {
        int row = m0 + wm + mi * 16 + quad * 4;
        #pragma unroll
        for (int ni = 0; ni < NB; ni++) {
            int col = n0 + wn + ni * 16 + l16;
            float bb = bias[col];
            if (QKV_EPI) {
                if (col < 2048) {
                    float sc2 = (col < 1024) ? SCL : 1.0f;
                    #pragma unroll
                    for (int r = 0; r < 4; r++)
                        ((ushort_t*)C)[(size_t)(row + r) * 2048 + col] =
                            f2bf((acc[mi][ni][r] + bb) * sc2);
                } else {
                    // V^T permuted: s' = (s&~31) | quad*8 | (mi&1)*4 | r
                    int s0v  = row & 2047;
                    int spos = (s0v & ~31) | (quad << 3) | ((mi & 1) << 2);
                    size_t vrow = (size_t)((row >> 11) * 1024 + (col - 2048));
                    float v0 = acc[mi][ni][0] + bb, v1 = acc[mi][ni][1] + bb;
                    float v2 = acc[mi][ni][2] + bb, v3 = acc[mi][ni][3] + bb;
                    uint2v pk;
                    pk.x = pack_bf16(v0, v1);
                    pk.y = pack_bf16(v2, v3);
                    *(uint2v*)(Vt_out + vrow * 2048 + spos) = pk;
                }
            } else {
                #pragma unroll
                for (int r = 0; r < 4; r++)
                    ((float*)C)[(size_t)(row + r) * N + col] = acc[mi][ni][r] + bb;
            }
        }
    }
}

// ---------------- flash attention v10 (frozen, passing): 8 waves / q-tile 128 --------
// qk bf16 [tok][2048] = [q(1024,pre-scaled) | k(1024)]; vt bf16 [bh*64+d][2048] s-permuted.
// grid (32 bh, 16 q-tiles) x 512 thr. Waves: qh=w>>1 (0..3, 32 q-rows each), kh=w&1.
// PV pipelined one tile behind QK; fp32 scalar lsum (bf16 ones-MFMA denominator fails
// numerics, r3); per-wave staging 1 K-row-block + 1 V-row-block per iter.
__global__ __launch_bounds__(512, 4)
void flash_attn_k(const ushort_t* __restrict__ qk, const ushort_t* __restrict__ vt,
                  ushort_t* __restrict__ out) {
    __shared__ char smem[49152];
    const int bh = blockIdx.x;
    const int b  = bh >> 4, h = bh & 15;
    const int q0 = blockIdx.y * 128;
    const int tid  = threadIdx.x;
    const int w    = tid >> 6;        // 0..7
    const int lane = tid & 63;
    const int quad = lane >> 4;
    const int l16  = lane & 15;
    const int qh   = w >> 1;          // 0..3
    const int kh   = w & 1;
    const size_t tok0 = (size_t)b * 2048;
    const int hq = h * 64;

    const int s7  = lane & 7;
    const int rk  = 8 * w + (lane >> 3);               // kv/d row 0..63
    const int ck  = (s7 ^ ((rk >> 1) & 7)) * 8;
    const int rq0 = 16 * w + (lane >> 3), rq1 = rq0 + 8;   // q rows 0..127
    const int cq0 = (s7 ^ ((rq0 >> 1) & 7)) * 8;
    const int cq1 = (s7 ^ ((rq1 >> 1) & 7)) * 8;
    const ushort_t* qg0 = qk + (tok0 + q0 + rq0) * 2048 + hq + cq0;
    const ushort_t* qg1 = qk + (tok0 + q0 + rq1) * 2048 + hq + cq1;
    const ushort_t* kg  = qk + (tok0 + rk) * 2048 + 1024 + hq + ck;
    const ushort_t* vg  = vt + (size_t)(bh * 64 + rk) * 2048 + ck;
    char* stK = smem + 1024 * w;
    char* stV = smem + 8192 + 1024 * w;
    char* stQ = smem + 32768 + 2048 * w;

    // prologue: Q -> Q area; K0/V0 -> B0
    GLD_LDS16(qg0, stQ);
    GLD_LDS16(qg1, stQ + 1024);
    GLD_LDS16(kg, stK);
    GLD_LDS16(vg, stV);
    __syncthreads();

    const int sw = (l16 >> 1) & 7;   // row-swizzle term for all frag reads
    short8 qf[2][2];
    #pragma unroll
    for (int sub = 0; sub < 2; sub++)
        #pragma unroll
        for (int kk = 0; kk < 2; kk++) {
            int row = qh * 32 + sub * 16 + l16;
            qf[sub][kk] = *(const short8*)(smem + 32768 + row * 128 +
                                           (((kk * 4 + quad) ^ sw) * 16));
        }

    int koff[2][2], voff[4];
    #pragma unroll
    for (int mi = 0; mi < 2; mi++)
        #pragma unroll
        for (int kk = 0; kk < 2; kk++) {
            int row = kh * 32 + mi * 16 + l16;
            koff[mi][kk] = row * 128 + (((kk * 4 + quad) ^ sw) * 16);
        }
    #pragma unroll
    for (int di = 0; di < 4; di++) {
        int row = di * 16 + l16;
        voff[di] = 8192 + row * 128 + (((kh * 4 + quad) ^ sw) * 16);
    }

    float4_ ot[2][4] = {};        // O^T: d = di*16+quad*4+r, q = qh*32+sub*16+l16
    float lsum[2] = {0.f, 0.f};
    short8 vprev[4];              // V frags of tile t-1 (time-shared reg block)
    short8 bpprev[2];             // packed P of tile t-1

    const ushort_t* kp = kg + (size_t)64 * 2048;
    const ushort_t* vp = vg + 64;

    // ---- peeled iter 0: QK(0), stash V(0)/P(0) in regs, no PV yet ----
    {
        __syncthreads();          // qf reads drained; DMA(0) done
        GLD_LDS16(kp, stK + 16384);
        GLD_LDS16(vp, stV + 16384);
        kp += (size_t)64 * 2048;
        vp += 64;
        const char* base = smem;
        float4_ st[2][2];
        #pragma unroll
        for (int mi = 0; mi < 2; mi++) {
            short8 kf0 = *(const short8*)(base + koff[mi][0]);
            short8 kf1 = *(const short8*)(base + koff[mi][1]);
            #pragma unroll
            for (int sub = 0; sub < 2; sub++) {
                float4_ z = {0.f, 0.f, 0.f, 0.f};
                z = MFMA32(kf0, qf[sub][0], z);
                z = MFMA32(kf1, qf[sub][1], z);
                st[mi][sub] = z;
            }
        }
        #pragma unroll
        for (int di = 0; di < 4; di++)
            vprev[di] = *(const short8*)(base + voff[di]);
        #pragma unroll
        for (int sub = 0; sub < 2; sub++) {
            uint4v u;
            #pragma unroll
            for (int mi = 0; mi < 2; mi++) {
                float p0 = __builtin_amdgcn_exp2f(st[mi][sub][0]);
                float p1 = __builtin_amdgcn_exp2f(st[mi][sub][1]);
                float p2 = __builtin_amdgcn_exp2f(st[mi][sub][2]);
                float p3 = __builtin_amdgcn_exp2f(st[mi][sub][3]);
                lsum[sub] += (p0 + p1) + (p2 + p3);
                if (mi == 0) { u.x = cvt_pk_bf16(p0, p1); u.y = cvt_pk_bf16(p2, p3); }
                else         { u.z = cvt_pk_bf16(p0, p1); u.w = cvt_pk_bf16(p2, p3); }
            }
            bpprev[sub] = __builtin_bit_cast(short8, u);
        }
    }

    // ---- main loop: tiles 1..31; PV runs one tile behind ----
    for (int kt = 64; kt < 2048; kt += 64) {
        __syncthreads();          // drains DMA(kt); tile(kt-64) LDS reads all done
        const int set = (kt >> 6) & 1;
        if (kt + 64 < 2048) {
            const int nb = (set ^ 1) * 16384;
            GLD_LDS16(kp, stK + nb);
            GLD_LDS16(vp, stV + nb);
            kp += (size_t)64 * 2048;
            vp += 64;
        }
        const char* base = smem + set * 16384;

        // QK(t): kv = kt + kh*32 + mi*16 + quad*4 + r, q = qh*32 + sub*16 + l16
        float4_ st[2][2];
        #pragma unroll
        for (int mi = 0; mi < 2; mi++) {
            short8 kf0 = *(const short8*)(base + koff[mi][0]);
            short8 kf1 = *(const short8*)(base + koff[mi][1]);
            #pragma unroll
            for (int sub = 0; sub < 2; sub++) {
                float4_ z = {0.f, 0.f, 0.f, 0.f};
                z = MFMA32(kf0, qf[sub][0], z);
                z = MFMA32(kf1, qf[sub][1], z);
                st[mi][sub] = z;
            }
        }

        // PV(t-1) from registers — independent of QK(t), hides its latency
        #pragma unroll
        for (int di = 0; di < 4; di++)
            #pragma unroll
            for (int sub = 0; sub < 2; sub++)
                ot[sub][di] = MFMA32(vprev[di], bpprev[sub], ot[sub][di]);

        // reload V(t) into the freed reg block (needed next iter)
        #pragma unroll
        for (int di = 0; di < 4; di++)
            vprev[di] = *(const short8*)(base + voff[di]);

        // exp/pack(t) -> bpprev, fp32 lsum (QK latency covered by PV MFMAs)
        #pragma unroll
        for (int sub = 0; sub < 2; sub++) {
            uint4v u;
            #pragma unroll
            for (int mi = 0; mi < 2; mi++) {
                float p0 = __builtin_amdgcn_exp2f(st[mi][sub][0]);
                float p1 = __builtin_amdgcn_exp2f(st[mi][sub][1]);
                float p2 = __builtin_amdgcn_exp2f(st[mi][sub][2]);
                float p3 = __builtin_amdgcn_exp2f(st[mi][sub][3]);
                lsum[sub] += (p0 + p1) + (p2 + p3);
                if (mi == 0) { u.x = cvt_pk_bf16(p0, p1); u.y = cvt_pk_bf16(p2, p3); }
                else         { u.z = cvt_pk_bf16(p0, p1); u.w = cvt_pk_bf16(p2, p3); }
            }
            bpprev[sub] = __builtin_bit_cast(short8, u);
        }
    }

    // ---- drain: PV(31) ----
    #pragma unroll
    for (int di = 0; di < 4; di++)
        #pragma unroll
        for (int sub = 0; sub < 2; sub++)
            ot[sub][di] = MFMA32(vprev[di], bpprev[sub], ot[sub][di]);

    // reduce l over quads
    #pragma unroll
    for (int sub = 0; sub < 2; sub++) {
        float t = lsum[sub];
        t += __shfl_xor(t, 16, 64);
        t += __shfl_xor(t, 32, 64);
        lsum[sub] = t;
    }

    // combine kv-halves across wave pairs through LDS (overlay on buffers)
    float* Obuf = (float*)smem;                 // [128][68]
    float* lbuf = (float*)(smem + 34816);       // [128][2]
    __syncthreads();                            // all buffer reads done
    #pragma unroll
    for (int sub = 0; sub < 2; sub++)
        lbuf[(qh * 32 + sub * 16 + l16) * 2 + kh] = lsum[sub];
    if (kh == 1) {
        #pragma unroll
        for (int sub = 0; sub < 2; sub++)
            #pragma unroll
            for (int di = 0; di < 4; di++)
                *(float4_*)&Obuf[(qh * 32 + sub * 16 + l16) * 68 + di * 16 + quad * 4] = ot[sub][di];
    }
    __syncthreads();
    if (kh == 0) {
        #pragma unroll
        for (int sub = 0; sub < 2; sub++)
            #pragma unroll
            for (int di = 0; di < 4; di++) {
                float4_* p = (float4_*)&Obuf[(qh * 32 + sub * 16 + l16) * 68 + di * 16 + quad * 4];
                *p = *p + ot[sub][di];
            }
    }
    __syncthreads();

    // normalize + coalesced store (512 thr -> 128 rows x 4 chunks)
    {
        int q  = tid >> 2;
        int ds = (tid & 3) * 16;
        float linv = 1.0f / (lbuf[q * 2] + lbuf[q * 2 + 1]);
        const float* ob = &Obuf[q * 68 + ds];
        float4_ v0 = *(const float4_*)(ob);
        float4_ v1 = *(const float4_*)(ob + 4);
        float4_ v2 = *(const float4_*)(ob + 8);
        float4_ v3 = *(const float4_*)(ob + 12);
        uint4v d0, d1;
        d0.x = pack_bf16(v0[0] * linv, v0[1] * linv);
        d0.y = pack_bf16(v0[2] * linv, v0[3] * linv);
        d0.z = pack_bf16(v1[0] * linv, v1[1] * linv);
        d0.w = pack_bf16(v1[2] * linv, v1[3] * linv);
        d1.x = pack_bf16(v2[0] * linv, v2[1] * linv);
        d1.y = pack_bf16(v2[2] * linv, v2[3] * linv);
        d1.z = pack_bf16(v3[0] * linv, v3[1] * linv);
        d1.w = pack_bf16(v3[2] * linv, v3[3] * linv);
        ushort_t* dst = out + (tok0 + q0 + (size_t)q) * 1024 + hq + ds;
        *(uint4v*)(dst)     = d0;
        *(uint4v*)(dst + 8) = d1;
    }
}

extern "C" void kernel_launch(void* const* d_in, const int* in_sizes, int n_in,
                              void* d_out, int out_size, void* d_ws, size_t ws_size,
                              hipStream_t stream) {
    const float* x    = (const float*)d_in[0];  // [2,2048,1024]
    const float* Wqkv = (const float*)d_in[1];  // [1024,3072]
    const float* bqkv = (const float*)d_in[2];  // [3072]
    const float* Wout = (const float*)d_in[3];  // [1024,1024]
    const float* bout = (const float*)d_in[4];  // [1024]
    float* out = (float*)d_out;                 // [2,2048,1024] fp32

    char* ws = (char*)d_ws;
    ushort_t* x_bf    = (ushort_t*)(ws);             // 8 MB
    ushort_t* WqkvT   = (ushort_t*)(ws + 8388608);   // 6 MB
    ushort_t* WoutT   = (ushort_t*)(ws + 14680064);  // 2 MB
    ushort_t* qk_bf   = (ushort_t*)(ws + 16777216);  // [4096][2048] = 16 MB
    ushort_t* vt_bf   = (ushort_t*)(ws + 33554432);  // [2048][2048] = 8 MB
    ushort_t* attn_bf = (ushort_t*)(ws + 41943040);  // 8 MB

    prep_k<<<6144, 256, 0, stream>>>(x, x_bf, Wqkv, WqkvT, Wout, WoutT);

    gemm_dbuf_k<128, true><<<dim3(24, 32), 256, 0, stream>>>(
        x_bf, WqkvT, bqkv, (void*)qk_bf, vt_bf, 4096, 3072, 1024);

    flash_attn_k<<<dim3(32, 16), 512, 0, stream>>>(qk_bf, vt_bf, attn_bf);

    // gemm2: TN=128 (same proven instantiation as gemm1 minus epilogue) — measured
    // tile-space at this structure: 64-wide ~343 TF vs 128² ~912 TF (m92/m103).
    // grid (8,32) = 256 blocks, nwg%8==0 for the XCD swizzle, 3 blocks/CU.
    gemm_dbuf_k<128, false><<<dim3(8, 32), 256, 0, stream>>>(
        attn_bf, WoutT, bout, (void*)out, nullptr, 4096, 1024, 1024);
}